// Round 17
// baseline (134.309 us; speedup 1.0000x reference)
//
#include <hip/hip_runtime.h>

typedef __bf16 bf16;
typedef bf16 bf16x8 __attribute__((ext_vector_type(8)));
typedef bf16 bf16x4 __attribute__((ext_vector_type(4)));
typedef float f32x4 __attribute__((ext_vector_type(4)));
typedef float f32x8 __attribute__((ext_vector_type(8)));
typedef float f32x16 __attribute__((ext_vector_type(16)));
typedef unsigned int u32;

#define BB 8
#define NN 2048
#define MM 4096

#if defined(__has_builtin)
#if __has_builtin(__builtin_amdgcn_exp2f)
#define EXP2(x) __builtin_amdgcn_exp2f(x)
#endif
#endif
#ifndef EXP2
#define EXP2(x) exp2f(x)
#endif

// ---------------------------------------------------------------------------
// Weight prep: W[k][n] f32 -> Wt[n][k] bf16  (4 matrices in one launch)
// ---------------------------------------------------------------------------
__global__ __launch_bounds__(256) void prep_wt(
    const float* W0, const float* W1, const float* W2, const float* W3,
    bf16* T0, bf16* T1, bf16* T2, bf16* T3) {
  const float* W; bf16* T;
  switch (blockIdx.y) {
    case 0:  W = W0; T = T0; break;
    case 1:  W = W1; T = T1; break;
    case 2:  W = W2; T = T2; break;
    default: W = W3; T = T3; break;
  }
  int n = blockIdx.x, k = threadIdx.x;
  T[n * 256 + k] = (bf16)W[k * 256 + n];
}

// ---------------------------------------------------------------------------
// Shared GEMM core: stages A (f32 or bf16-headsplit) and Wt into swizzled LDS,
// accumulates 128x128 tile via 16x16x32 MFMA.
// ---------------------------------------------------------------------------
#define GEMM_CORE(AM, Aptr, Wtp, row0, col0)                                  \
  for (int k0 = 0; k0 < 256; k0 += 64) {                                      \
    __syncthreads();                                                          \
    if (AM == 0) {                                                            \
      const float* Af = (const float*)(Aptr);                                 \
      _Pragma("unroll")                                                       \
      for (int i = 0; i < 8; ++i) {                                           \
        int idx = t + i * 256;                                                \
        int m = idx >> 4, c4 = idx & 15;                                      \
        f32x4 v = *(const f32x4*)(Af + (size_t)((row0) + m) * 256 + k0 + c4 * 4); \
        bf16x4 bv;                                                            \
        _Pragma("unroll")                                                     \
        for (int j = 0; j < 4; ++j) bv[j] = (bf16)v[j];                       \
        *(bf16x4*)((char*)As + m * 128 + ((c4 * 8) ^ ((m & 7) << 4))) = bv;   \
      }                                                                       \
    } else {                                                                  \
      const bf16* Ab = (const bf16*)(Aptr);                                   \
      _Pragma("unroll")                                                       \
      for (int i = 0; i < 4; ++i) {                                           \
        int idx = t + i * 256;                                                \
        int m = idx >> 3, c = idx & 7;                                        \
        int r = (row0) + m;                                                   \
        int b = r >> 11, nl = r & 2047, h = k0 >> 6;                          \
        const bf16* src = Ab + ((size_t)(b * 4 + h) * 2048 + nl) * 64 + c * 8;\
        bf16x8 v = *(const bf16x8*)src;                                       \
        *(bf16x8*)((char*)As + m * 128 + ((c * 16) ^ ((m & 7) << 4))) = v;    \
      }                                                                       \
    }                                                                         \
    _Pragma("unroll")                                                         \
    for (int i = 0; i < 4; ++i) {                                             \
      int idx = t + i * 256;                                                  \
      int n = idx >> 3, c = idx & 7;                                          \
      bf16x8 v = *(const bf16x8*)((Wtp) + (size_t)((col0) + n) * 256 + k0 + c * 8); \
      *(bf16x8*)((char*)Bs + n * 128 + ((c * 16) ^ ((n & 7) << 4))) = v;      \
    }                                                                         \
    __syncthreads();                                                          \
    _Pragma("unroll")                                                         \
    for (int kh = 0; kh < 2; ++kh) {                                          \
      bf16x8 a[4], b[4];                                                      \
      _Pragma("unroll")                                                       \
      for (int mi = 0; mi < 4; ++mi) {                                        \
        int row = wm + mi * 16 + l15;                                         \
        a[mi] = *(const bf16x8*)((char*)As + row * 128 + ((kh * 64 + lhi * 16) ^ (l7 << 4))); \
      }                                                                       \
      _Pragma("unroll")                                                       \
      for (int ni = 0; ni < 4; ++ni) {                                        \
        int row = wn + ni * 16 + l15;                                         \
        b[ni] = *(const bf16x8*)((char*)Bs + row * 128 + ((kh * 64 + lhi * 16) ^ (l7 << 4))); \
      }                                                                       \
      _Pragma("unroll")                                                       \
      for (int mi = 0; mi < 4; ++mi)                                          \
        _Pragma("unroll")                                                     \
        for (int ni = 0; ni < 4; ++ni)                                        \
          acc[mi][ni] = __builtin_amdgcn_mfma_f32_16x16x32_bf16(a[mi], b[ni], acc[mi][ni], 0, 0, 0); \
    }                                                                         \
  }

// ---------------------------------------------------------------------------
// Fused Q + K/V projection GEMM, one launch (1280 blocks), XCD-chunked:
//   blocks [0,256):    Q = (nuc @ Wq + bq)*qscale -> head-split bf16
//   blocks [256,1280): KV = ele @ Wkv + b -> K/V LDS-image layout
// ---------------------------------------------------------------------------
__global__ __launch_bounds__(256) void gemm_qkv(
    const float* __restrict__ nuc, const float* __restrict__ ele,
    const bf16* __restrict__ wtq, const bf16* __restrict__ wtkv,
    const float* __restrict__ bq, const float* __restrict__ bk,
    const float* __restrict__ bv, bf16* __restrict__ qhs,
    char* __restrict__ kvt, float qscale) {
  __shared__ __align__(16) char smem[32768];
  bf16* As = (bf16*)smem;
  bf16* Bs = (bf16*)(smem + 16384);
  const int t = threadIdx.x;
  const int lane = t & 63, wid = t >> 6;
  const int l15 = lane & 15, lhi = lane >> 4, l7 = lane & 7;
  const int wm = (wid >> 1) * 64, wn = (wid & 1) * 64;

  const int bidx = blockIdx.x;
  const bool isQ = (bidx < 256);
  int row0, col0;
  const float* A;
  const bf16* Wt;
  if (isQ) {
    int lg = (bidx & 7) * 32 + (bidx >> 3);      // 256 blocks, 32/XCD
    row0 = (lg >> 1) * 128; col0 = (lg & 1) * 128; A = nuc; Wt = wtq;
  } else {
    int j = bidx - 256;                          // (bidx&7)==(j&7): 256%8==0
    int lg = (j & 7) * 128 + (j >> 3);           // 1024 blocks, 128/XCD
    row0 = (lg >> 2) * 128; col0 = (lg & 3) * 128; A = ele; Wt = wtkv;
  }

  f32x4 zero4 = {0.f, 0.f, 0.f, 0.f};
  f32x4 acc[4][4];
#pragma unroll
  for (int i = 0; i < 4; ++i)
#pragma unroll
    for (int j = 0; j < 4; ++j) acc[i][j] = zero4;

  GEMM_CORE(0, A, Wt, row0, col0)

  if (isQ) {
#pragma unroll
    for (int mi = 0; mi < 4; ++mi)
#pragma unroll
      for (int ni = 0; ni < 4; ++ni) {
        int n = col0 + wn + ni * 16 + l15;
        float bvv = bq[n];
#pragma unroll
        for (int r = 0; r < 4; ++r) {
          int mrow = row0 + wm + mi * 16 + lhi * 4 + r;
          float val = (acc[mi][ni][r] + bvv) * qscale;
          int b = mrow >> 11, nl = mrow & 2047;
          qhs[((size_t)(b * 4 + (n >> 6)) * 2048 + nl) * 64 + (n & 63)] = (bf16)val;
        }
      }
  } else {
    __syncthreads();   // done with As/Bs; reuse smem as image stage
#pragma unroll
    for (int mi = 0; mi < 4; ++mi)
#pragma unroll
      for (int ni = 0; ni < 4; ++ni) {
        int n = col0 + wn + ni * 16 + l15;
        float bvv = (n < 256) ? bk[n] : bv[n - 256];
#pragma unroll
        for (int r = 0; r < 4; ++r) {
          float val = acc[mi][ni][r] + bvv;
          int dm = wm + mi * 16 + lhi * 4 + r;     // 0..127
          int dn = wn + ni * 16 + l15;             // 0..127
          int dkt = dm >> 6, kvl = dm & 63;
          int d = dn & 63;
          int inner;
          if (col0 < 256)  // K image: [kv>>5][d>>3][kv&31][d&7]
            inner = (((kvl >> 5) & 1) << 12) + ((d >> 3) << 9)
                  + ((kvl & 31) << 4) + ((d & 7) << 1);
          else             // V image: [d>>5][(kv>>3)&7][d&31][kv&7]
            inner = ((d >> 5) << 12) + (((kvl >> 3) & 7) << 9)
                  + ((d & 31) << 4) + ((kvl & 7) << 1);
          *(bf16*)(smem + (dkt * 2 + (dn >> 6)) * 8192 + inner) = (bf16)val;
        }
      }
    __syncthreads();
    const int isK = (col0 < 256);
    int b = row0 >> 12, kt0 = (row0 & 4095) >> 6, h0 = (col0 & 255) >> 6;
#pragma unroll
    for (int c = 0; c < 4; ++c) {
      int dkt = c >> 1, dh = c & 1;
      char* dst = kvt + ((size_t)((b * 4 + h0 + dh) * 64 + kt0 + dkt)) * 16384
                  + (isK ? 0 : 8192);
      *(bf16x8*)(dst + t * 16)        = *(const bf16x8*)(smem + c * 8192 + t * 16);
      *(bf16x8*)(dst + 4096 + t * 16) = *(const bf16x8*)(smem + c * 8192 + 4096 + t * 16);
    }
  }
}

// ---------------------------------------------------------------------------
// Output projection GEMM: out = aoh @ Wo + bo  (f32 flat), XCD-chunked 1D grid
// ---------------------------------------------------------------------------
__global__ __launch_bounds__(256) void gemm_out(
    const bf16* __restrict__ aoh, const bf16* __restrict__ wto,
    const float* __restrict__ bo, float* __restrict__ out) {
  __shared__ __align__(16) char smem[32768];
  bf16* As = (bf16*)smem;
  bf16* Bs = (bf16*)(smem + 16384);
  const int t = threadIdx.x;
  const int lane = t & 63, wid = t >> 6;
  const int l15 = lane & 15, lhi = lane >> 4, l7 = lane & 7;
  const int lg = (blockIdx.x & 7) * 32 + (blockIdx.x >> 3);   // 256 blocks
  const int row0 = (lg >> 1) * 128, col0 = (lg & 1) * 128;
  const int wm = (wid >> 1) * 64, wn = (wid & 1) * 64;

  f32x4 zero4 = {0.f, 0.f, 0.f, 0.f};
  f32x4 acc[4][4];
#pragma unroll
  for (int i = 0; i < 4; ++i)
#pragma unroll
    for (int j = 0; j < 4; ++j) acc[i][j] = zero4;

  GEMM_CORE(1, aoh, wto, row0, col0)

#pragma unroll
  for (int mi = 0; mi < 4; ++mi)
#pragma unroll
    for (int ni = 0; ni < 4; ++ni) {
      int n = col0 + wn + ni * 16 + l15;
      float bvv = bo[n];
#pragma unroll
      for (int r = 0; r < 4; ++r) {
        int mrow = row0 + wm + mi * 16 + lhi * 4 + r;
        out[(size_t)mrow * 256 + n] = acc[mi][ni][r] + bvv;
      }
    }
}

// ---------------------------------------------------------------------------
// Flash cross-attention — r12 structure (94.2us) + l-sum moved to MFMA pipe:
// an all-ones A-fragment MFMA accumulates l[q] = sum_kv P[kv][q] in O2
// (every output row equals l), replacing 32 VALU adds/iter + epilogue tree.
// ---------------------------------------------------------------------------
__device__ __forceinline__ u32 pkbf(float a, float b) {
  union { bf16 h[2]; u32 u; } p;
  p.h[0] = (bf16)a; p.h[1] = (bf16)b;
  return p.u;
}

__global__ __launch_bounds__(512) void attn_kernel(
    const bf16* __restrict__ q, const char* __restrict__ kvt,
    bf16* __restrict__ ao) {
  __shared__ __align__(16) char lds[2][2][16384];   // [kvh][buf][tile image]
  __shared__ float Ll[8][32];
  const int t = threadIdx.x;
  const int lane = t & 63, wid = t >> 6;
  const int l31 = lane & 31, lhi1 = lane >> 5;
  const int bid = blockIdx.x;
  const int xcd = bid & 7, rem = bid >> 3;     // XCD-aware swizzle: 4 bh/XCD
  const int bh = (xcd << 2) + (rem >> 4);
  const int q0 = (rem & 15) * 128;
  const int qt = wid >> 1, kvh = wid & 1;

  // Q B-fragments: lane holds q=l31, d = kc*16 + lhi1*8 + j
  bf16x8 qf[4];
  {
    const bf16* qp = q + ((size_t)bh * NN + q0 + qt * 32 + l31) * 64 + lhi1 * 8;
#pragma unroll
    for (int c = 0; c < 4; ++c) qf[c] = *(const bf16x8*)(qp + c * 16);
  }

  bf16x8 ones;
#pragma unroll
  for (int j = 0; j < 8; ++j) ones[j] = (bf16)1.0f;

  // staging: wave stages quarter qt of its kv-group's tile (4KB = 4x16B/lane)
  const char* sp = kvt + ((size_t)(bh * 64 + kvh * 32)) * 16384 + qt * 4096 + lane * 16;
  char* wp0 = &lds[kvh][0][qt * 4096 + lane * 16];
  char* wp1 = &lds[kvh][1][qt * 4096 + lane * 16];
  const char* KB0 = &lds[kvh][0][0];
  const char* KB1 = &lds[kvh][1][0];

  f32x16 O0 = {}, O1 = {}, O2 = {};

  bf16x8 st0, st1, st2, st3;
#define SLOAD()                                                           \
  {                                                                       \
    st0 = *(const bf16x8*)(sp);                                           \
    st1 = *(const bf16x8*)(sp + 1024);                                    \
    st2 = *(const bf16x8*)(sp + 2048);                                    \
    st3 = *(const bf16x8*)(sp + 3072);                                    \
    sp += 16384;                                                          \
  }
#define SWRITE(WP)                                                       \
  {                                                                       \
    *(bf16x8*)(WP) = st0;                                                 \
    *(bf16x8*)((WP) + 1024) = st1;                                        \
    *(bf16x8*)((WP) + 2048) = st2;                                        \
    *(bf16x8*)((WP) + 3072) = st3;                                        \
  }

  auto compute = [&](const char* KB) {
    const char* VB = KB + 8192;
    // ---- S^T: mfma(A=K rows, B=Q); contiguous 1KB frag reads ----
    f32x16 s0 = {}, s1 = {};
    __builtin_amdgcn_s_setprio(1);
#pragma unroll
    for (int kc = 0; kc < 4; ++kc) {
      bf16x8 k0 = *(const bf16x8*)(KB + ((2 * kc + lhi1) << 9) + l31 * 16);
      bf16x8 k1 = *(const bf16x8*)(KB + 4096 + ((2 * kc + lhi1) << 9) + l31 * 16);
      s0 = __builtin_amdgcn_mfma_f32_32x32x16_bf16(k0, qf[kc], s0, 0, 0, 0);
      s1 = __builtin_amdgcn_mfma_f32_32x32x16_bf16(k1, qf[kc], s1, 0, 0, 0);
    }
    __builtin_amdgcn_s_setprio(0);

    // ---- P = exp2(S) (fixed max, raw v_exp_f32) ----
#pragma unroll
    for (int r = 0; r < 16; ++r) {
      s0[r] = EXP2(s0[r]);
      s1[r] = EXP2(s1[r]);
    }

    // ---- pack P to bf16 words: w(s,rr) = P[kv=8s+4lhi1+2rr+{0,1}][q] ----
    u32 w0[8], w1[8];
#pragma unroll
    for (int s = 0; s < 4; ++s)
#pragma unroll
      for (int rr = 0; rr < 2; ++rr) {
        w0[s * 2 + rr] = pkbf(s0[4 * s + 2 * rr], s0[4 * s + 2 * rr + 1]);
        w1[s * 2 + rr] = pkbf(s1[4 * s + 2 * rr], s1[4 * s + 2 * rr + 1]);
      }

    // ---- PV via native 32x32x16; exchange via v_permlane32_swap_b32 ----
    // O2 += mfma(ones, P): every row of O2 accumulates l[q] (MFMA-pipe l-sum)
    __builtin_amdgcn_s_setprio(1);
#pragma unroll
    for (int t2 = 0; t2 < 2; ++t2) {
#pragma unroll
      for (int c2 = 0; c2 < 2; ++c2) {
        u32 aw0 = t2 ? w1[4 * c2 + 0] : w0[4 * c2 + 0];
        u32 aw1 = t2 ? w1[4 * c2 + 1] : w0[4 * c2 + 1];
        u32 bw0 = t2 ? w1[4 * c2 + 2] : w0[4 * c2 + 2];
        u32 bw1 = t2 ? w1[4 * c2 + 3] : w0[4 * c2 + 3];
        // swap(vdst=aw, vsrc=bw): aw'={aw.lo,bw.lo}=pb.u[0]; bw'={aw.hi,bw.hi}=pb.u[2]
        asm("v_permlane32_swap_b32 %0, %1" : "+v"(aw0), "+v"(bw0));
        asm("v_permlane32_swap_b32 %0, %1" : "+v"(aw1), "+v"(bw1));
        union { u32 u[4]; bf16x8 v; } pb;
        pb.u[0] = aw0;
        pb.u[1] = aw1;
        pb.u[2] = bw0;
        pb.u[3] = bw1;
        const int kb = t2 * 2 + c2;
        int base = ((2 * kb + lhi1) << 9) + l31 * 16;
        bf16x8 va = *(const bf16x8*)(VB + base);
        bf16x8 vb = *(const bf16x8*)(VB + 4096 + base);
        O0 = __builtin_amdgcn_mfma_f32_32x32x16_bf16(va, pb.v, O0, 0, 0, 0);
        O1 = __builtin_amdgcn_mfma_f32_32x32x16_bf16(vb, pb.v, O1, 0, 0, 0);
        O2 = __builtin_amdgcn_mfma_f32_32x32x16_bf16(ones, pb.v, O2, 0, 0, 0);
      }
    }
    __builtin_amdgcn_s_setprio(0);
  };

  // ---- prologue: tile0 -> buf0 ----
  SLOAD(); SWRITE(wp0);
  __syncthreads();

  // ---- main loop, unrolled x2: static buffer pointers ----
  for (int kt = 0; kt < 32; kt += 2) {
    SLOAD();                         // tile kt+1
    compute(KB0);                    // tile kt
    SWRITE(wp1);
    __syncthreads();
    if (kt + 2 < 32) SLOAD();        // tile kt+2
    compute(KB1);                    // tile kt+1
    if (kt + 2 < 32) SWRITE(wp0);
    __syncthreads();
  }

  // ---- l for this kv-half: every O2 element equals l[q=l31] ----
  float l = O2[0];

  // ---- merge the two kv-halves of each q-tile via LDS (pure add) ----
  float* Olf = (float*)&lds[0][0][0];          // [8][64][32] f32 = 64KB
#pragma unroll
  for (int t2 = 0; t2 < 2; ++t2)
#pragma unroll
    for (int r = 0; r < 16; ++r) {
      int d = t2 * 32 + (r & 3) + 8 * (r >> 2) + 4 * lhi1;
      Olf[wid * 2048 + d * 32 + l31] = t2 ? O1[r] : O0[r];
    }
  if (lane < 32) Ll[wid][l31] = l;
  __syncthreads();

  const int pw = wid ^ 1;
  float inv = 1.f / (l + Ll[pw][l31]);
  const int dth = kvh;
  f32x16 Os = dth ? O1 : O0;
  bf16* op = ao + ((size_t)bh * NN + q0 + qt * 32 + l31) * 64 + dth * 32 + 4 * lhi1;
#pragma unroll
  for (int rg = 0; rg < 4; ++rg) {
    bf16x4 ov;
#pragma unroll
    for (int e = 0; e < 4; ++e) {
      int r = rg * 4 + e;
      int d = dth * 32 + e + 8 * rg + 4 * lhi1;
      float comb = Os[r] + Olf[pw * 2048 + d * 32 + l31];
      ov[e] = (bf16)(comb * inv);
    }
    *(bf16x4*)(op + 8 * rg) = ov;
  }
#undef SLOAD
#undef SWRITE
}

// ---------------------------------------------------------------------------
extern "C" void kernel_launch(void* const* d_in, const int* in_sizes, int n_in,
                              void* d_out, int out_size, void* d_ws, size_t ws_size,
                              hipStream_t stream) {
  const float* nuc = (const float*)d_in[0];
  const float* ele = (const float*)d_in[1];
  const float* Wq  = (const float*)d_in[2];
  const float* bq  = (const float*)d_in[3];
  const float* Wk  = (const float*)d_in[4];
  const float* bk  = (const float*)d_in[5];
  const float* Wv  = (const float*)d_in[6];
  const float* bv  = (const float*)d_in[7];
  const float* Wo  = (const float*)d_in[8];
  const float* bo  = (const float*)d_in[9];
  float* out = (float*)d_out;
  char* ws = (char*)d_ws;

  bf16* wtq  = (bf16*)(ws + 0);
  bf16* wtkv = (bf16*)(ws + 131072);     // wtk / wtv adjacent
  bf16* wtk  = (bf16*)(ws + 131072);
  bf16* wtv  = (bf16*)(ws + 262144);
  bf16* wto  = (bf16*)(ws + 393216);
  bf16* qhs  = (bf16*)(ws + 524288);     // [32][2048][64] bf16, 8MB
  char* kvt  = (char*)(ws + 8912896);    // [32][64][16KB] K/V images, 32MB
  bf16* aoh  = (bf16*)(ws + 42467328);   // [32][2048][64] bf16, 8MB

  prep_wt<<<dim3(256, 4), 256, 0, stream>>>(Wq, Wk, Wv, Wo, wtq, wtk, wtv, wto);

  // fused Q + K/V projections (Q scaled by 1/sqrt(64)*log2(e) for exp2 domain)
  gemm_qkv<<<dim3(1280), 256, 0, stream>>>(nuc, ele, wtq, wtkv, bq, bk, bv,
                                           qhs, kvt, 0.18033688011112042f);

  attn_kernel<<<dim3(512), 512, 0, stream>>>(qhs, kvt, aoh);

  gemm_out<<<dim3(256), 256, 0, stream>>>(aoh, wto, bo, out);
}

// Round 18
// 131.322 us; speedup vs baseline: 1.0227x; 1.0227x over previous
//
#include <hip/hip_runtime.h>

typedef __bf16 bf16;
typedef bf16 bf16x8 __attribute__((ext_vector_type(8)));
typedef bf16 bf16x4 __attribute__((ext_vector_type(4)));
typedef float f32x4 __attribute__((ext_vector_type(4)));
typedef float f32x8 __attribute__((ext_vector_type(8)));
typedef float f32x16 __attribute__((ext_vector_type(16)));
typedef unsigned int u32;

#define BB 8
#define NN 2048
#define MM 4096

#if defined(__has_builtin)
#if __has_builtin(__builtin_amdgcn_exp2f)
#define EXP2(x) __builtin_amdgcn_exp2f(x)
#endif
#endif
#ifndef EXP2
#define EXP2(x) exp2f(x)
#endif

// ---------------------------------------------------------------------------
// Weight prep: W[k][n] f32 -> Wt[n][k] bf16  (4 matrices in one launch)
// ---------------------------------------------------------------------------
__global__ __launch_bounds__(256) void prep_wt(
    const float* W0, const float* W1, const float* W2, const float* W3,
    bf16* T0, bf16* T1, bf16* T2, bf16* T3) {
  const float* W; bf16* T;
  switch (blockIdx.y) {
    case 0:  W = W0; T = T0; break;
    case 1:  W = W1; T = T1; break;
    case 2:  W = W2; T = T2; break;
    default: W = W3; T = T3; break;
  }
  int n = blockIdx.x, k = threadIdx.x;
  T[n * 256 + k] = (bf16)W[k * 256 + n];
}

// ---------------------------------------------------------------------------
// Shared GEMM core: stages A (f32 or bf16-headsplit) and Wt into swizzled LDS,
// accumulates 128x128 tile via 16x16x32 MFMA.
// ---------------------------------------------------------------------------
#define GEMM_CORE(AM, Aptr, Wtp, row0, col0)                                  \
  for (int k0 = 0; k0 < 256; k0 += 64) {                                      \
    __syncthreads();                                                          \
    if (AM == 0) {                                                            \
      const float* Af = (const float*)(Aptr);                                 \
      _Pragma("unroll")                                                       \
      for (int i = 0; i < 8; ++i) {                                           \
        int idx = t + i * 256;                                                \
        int m = idx >> 4, c4 = idx & 15;                                      \
        f32x4 v = *(const f32x4*)(Af + (size_t)((row0) + m) * 256 + k0 + c4 * 4); \
        bf16x4 bv;                                                            \
        _Pragma("unroll")                                                     \
        for (int j = 0; j < 4; ++j) bv[j] = (bf16)v[j];                       \
        *(bf16x4*)((char*)As + m * 128 + ((c4 * 8) ^ ((m & 7) << 4))) = bv;   \
      }                                                                       \
    } else {                                                                  \
      const bf16* Ab = (const bf16*)(Aptr);                                   \
      _Pragma("unroll")                                                       \
      for (int i = 0; i < 4; ++i) {                                           \
        int idx = t + i * 256;                                                \
        int m = idx >> 3, c = idx & 7;                                        \
        int r = (row0) + m;                                                   \
        int b = r >> 11, nl = r & 2047, h = k0 >> 6;                          \
        const bf16* src = Ab + ((size_t)(b * 4 + h) * 2048 + nl) * 64 + c * 8;\
        bf16x8 v = *(const bf16x8*)src;                                       \
        *(bf16x8*)((char*)As + m * 128 + ((c * 16) ^ ((m & 7) << 4))) = v;    \
      }                                                                       \
    }                                                                         \
    _Pragma("unroll")                                                         \
    for (int i = 0; i < 4; ++i) {                                             \
      int idx = t + i * 256;                                                  \
      int n = idx >> 3, c = idx & 7;                                          \
      bf16x8 v = *(const bf16x8*)((Wtp) + (size_t)((col0) + n) * 256 + k0 + c * 8); \
      *(bf16x8*)((char*)Bs + n * 128 + ((c * 16) ^ ((n & 7) << 4))) = v;      \
    }                                                                         \
    __syncthreads();                                                          \
    _Pragma("unroll")                                                         \
    for (int kh = 0; kh < 2; ++kh) {                                          \
      bf16x8 a[4], b[4];                                                      \
      _Pragma("unroll")                                                       \
      for (int mi = 0; mi < 4; ++mi) {                                        \
        int row = wm + mi * 16 + l15;                                         \
        a[mi] = *(const bf16x8*)((char*)As + row * 128 + ((kh * 64 + lhi * 16) ^ (l7 << 4))); \
      }                                                                       \
      _Pragma("unroll")                                                       \
      for (int ni = 0; ni < 4; ++ni) {                                        \
        int row = wn + ni * 16 + l15;                                         \
        b[ni] = *(const bf16x8*)((char*)Bs + row * 128 + ((kh * 64 + lhi * 16) ^ (l7 << 4))); \
      }                                                                       \
      _Pragma("unroll")                                                       \
      for (int mi = 0; mi < 4; ++mi)                                          \
        _Pragma("unroll")                                                     \
        for (int ni = 0; ni < 4; ++ni)                                        \
          acc[mi][ni] = __builtin_amdgcn_mfma_f32_16x16x32_bf16(a[mi], b[ni], acc[mi][ni], 0, 0, 0); \
    }                                                                         \
  }

// ---------------------------------------------------------------------------
// Fused Q + K/V projection GEMM, one launch (1280 blocks), XCD-chunked:
//   blocks [0,256):    Q = (nuc @ Wq + bq)*qscale -> head-split bf16
//   blocks [256,1280): KV = ele @ Wkv + b -> K/V LDS-image layout
// ---------------------------------------------------------------------------
__global__ __launch_bounds__(256) void gemm_qkv(
    const float* __restrict__ nuc, const float* __restrict__ ele,
    const bf16* __restrict__ wtq, const bf16* __restrict__ wtkv,
    const float* __restrict__ bq, const float* __restrict__ bk,
    const float* __restrict__ bv, bf16* __restrict__ qhs,
    char* __restrict__ kvt, float qscale) {
  __shared__ __align__(16) char smem[32768];
  bf16* As = (bf16*)smem;
  bf16* Bs = (bf16*)(smem + 16384);
  const int t = threadIdx.x;
  const int lane = t & 63, wid = t >> 6;
  const int l15 = lane & 15, lhi = lane >> 4, l7 = lane & 7;
  const int wm = (wid >> 1) * 64, wn = (wid & 1) * 64;

  const int bidx = blockIdx.x;
  const bool isQ = (bidx < 256);
  int row0, col0;
  const float* A;
  const bf16* Wt;
  if (isQ) {
    int lg = (bidx & 7) * 32 + (bidx >> 3);      // 256 blocks, 32/XCD
    row0 = (lg >> 1) * 128; col0 = (lg & 1) * 128; A = nuc; Wt = wtq;
  } else {
    int j = bidx - 256;                          // (bidx&7)==(j&7): 256%8==0
    int lg = (j & 7) * 128 + (j >> 3);           // 1024 blocks, 128/XCD
    row0 = (lg >> 2) * 128; col0 = (lg & 3) * 128; A = ele; Wt = wtkv;
  }

  f32x4 zero4 = {0.f, 0.f, 0.f, 0.f};
  f32x4 acc[4][4];
#pragma unroll
  for (int i = 0; i < 4; ++i)
#pragma unroll
    for (int j = 0; j < 4; ++j) acc[i][j] = zero4;

  GEMM_CORE(0, A, Wt, row0, col0)

  if (isQ) {
#pragma unroll
    for (int mi = 0; mi < 4; ++mi)
#pragma unroll
      for (int ni = 0; ni < 4; ++ni) {
        int n = col0 + wn + ni * 16 + l15;
        float bvv = bq[n];
#pragma unroll
        for (int r = 0; r < 4; ++r) {
          int mrow = row0 + wm + mi * 16 + lhi * 4 + r;
          float val = (acc[mi][ni][r] + bvv) * qscale;
          int b = mrow >> 11, nl = mrow & 2047;
          qhs[((size_t)(b * 4 + (n >> 6)) * 2048 + nl) * 64 + (n & 63)] = (bf16)val;
        }
      }
  } else {
    __syncthreads();   // done with As/Bs; reuse smem as image stage
#pragma unroll
    for (int mi = 0; mi < 4; ++mi)
#pragma unroll
      for (int ni = 0; ni < 4; ++ni) {
        int n = col0 + wn + ni * 16 + l15;
        float bvv = (n < 256) ? bk[n] : bv[n - 256];
#pragma unroll
        for (int r = 0; r < 4; ++r) {
          float val = acc[mi][ni][r] + bvv;
          int dm = wm + mi * 16 + lhi * 4 + r;     // 0..127
          int dn = wn + ni * 16 + l15;             // 0..127
          int dkt = dm >> 6, kvl = dm & 63;
          int d = dn & 63;
          int inner;
          if (col0 < 256)  // K image: [kv>>5][d>>3][kv&31][d&7]
            inner = (((kvl >> 5) & 1) << 12) + ((d >> 3) << 9)
                  + ((kvl & 31) << 4) + ((d & 7) << 1);
          else             // V image: [d>>5][(kv>>3)&7][d&31][kv&7]
            inner = ((d >> 5) << 12) + (((kvl >> 3) & 7) << 9)
                  + ((d & 31) << 4) + ((kvl & 7) << 1);
          *(bf16*)(smem + (dkt * 2 + (dn >> 6)) * 8192 + inner) = (bf16)val;
        }
      }
    __syncthreads();
    const int isK = (col0 < 256);
    int b = row0 >> 12, kt0 = (row0 & 4095) >> 6, h0 = (col0 & 255) >> 6;
#pragma unroll
    for (int c = 0; c < 4; ++c) {
      int dkt = c >> 1, dh = c & 1;
      char* dst = kvt + ((size_t)((b * 4 + h0 + dh) * 64 + kt0 + dkt)) * 16384
                  + (isK ? 0 : 8192);
      *(bf16x8*)(dst + t * 16)        = *(const bf16x8*)(smem + c * 8192 + t * 16);
      *(bf16x8*)(dst + 4096 + t * 16) = *(const bf16x8*)(smem + c * 8192 + 4096 + t * 16);
    }
  }
}

// ---------------------------------------------------------------------------
// Output projection GEMM: out = aoh @ Wo + bo  (f32 flat), XCD-chunked 1D grid
// ---------------------------------------------------------------------------
__global__ __launch_bounds__(256) void gemm_out(
    const bf16* __restrict__ aoh, const bf16* __restrict__ wto,
    const float* __restrict__ bo, float* __restrict__ out) {
  __shared__ __align__(16) char smem[32768];
  bf16* As = (bf16*)smem;
  bf16* Bs = (bf16*)(smem + 16384);
  const int t = threadIdx.x;
  const int lane = t & 63, wid = t >> 6;
  const int l15 = lane & 15, lhi = lane >> 4, l7 = lane & 7;
  const int lg = (blockIdx.x & 7) * 32 + (blockIdx.x >> 3);   // 256 blocks
  const int row0 = (lg >> 1) * 128, col0 = (lg & 1) * 128;
  const int wm = (wid >> 1) * 64, wn = (wid & 1) * 64;

  f32x4 zero4 = {0.f, 0.f, 0.f, 0.f};
  f32x4 acc[4][4];
#pragma unroll
  for (int i = 0; i < 4; ++i)
#pragma unroll
    for (int j = 0; j < 4; ++j) acc[i][j] = zero4;

  GEMM_CORE(1, aoh, wto, row0, col0)

#pragma unroll
  for (int mi = 0; mi < 4; ++mi)
#pragma unroll
    for (int ni = 0; ni < 4; ++ni) {
      int n = col0 + wn + ni * 16 + l15;
      float bvv = bo[n];
#pragma unroll
      for (int r = 0; r < 4; ++r) {
        int mrow = row0 + wm + mi * 16 + lhi * 4 + r;
        out[(size_t)mrow * 256 + n] = acc[mi][ni][r] + bvv;
      }
    }
}

// ---------------------------------------------------------------------------
// Flash cross-attention — round-12 structure (measured floor 94.2us):
// swapped-operand, LDS-image K/V tiles, kv-split x2, 8 waves, setprio,
// fixed-max softmax (exp2 domain, raw v_exp_f32), static buffer pointers,
// PV via native 32x32x16 + v_permlane32_swap_b32 exchange, VALU psum.
// (r13 occupancy-restructure, r14 deep-pipeline, r17 MFMA-l-sum all regressed)
// ---------------------------------------------------------------------------
__device__ __forceinline__ u32 pkbf(float a, float b) {
  union { bf16 h[2]; u32 u; } p;
  p.h[0] = (bf16)a; p.h[1] = (bf16)b;
  return p.u;
}

__global__ __launch_bounds__(512) void attn_kernel(
    const bf16* __restrict__ q, const char* __restrict__ kvt,
    bf16* __restrict__ ao) {
  __shared__ __align__(16) char lds[2][2][16384];   // [kvh][buf][tile image]
  __shared__ float Ll[8][32];
  const int t = threadIdx.x;
  const int lane = t & 63, wid = t >> 6;
  const int l31 = lane & 31, lhi1 = lane >> 5;
  const int bid = blockIdx.x;
  const int xcd = bid & 7, rem = bid >> 3;     // XCD-aware swizzle: 4 bh/XCD
  const int bh = (xcd << 2) + (rem >> 4);
  const int q0 = (rem & 15) * 128;
  const int qt = wid >> 1, kvh = wid & 1;

  // Q B-fragments: lane holds q=l31, d = kc*16 + lhi1*8 + j
  bf16x8 qf[4];
  {
    const bf16* qp = q + ((size_t)bh * NN + q0 + qt * 32 + l31) * 64 + lhi1 * 8;
#pragma unroll
    for (int c = 0; c < 4; ++c) qf[c] = *(const bf16x8*)(qp + c * 16);
  }

  // staging: wave stages quarter qt of its kv-group's tile (4KB = 4x16B/lane)
  const char* sp = kvt + ((size_t)(bh * 64 + kvh * 32)) * 16384 + qt * 4096 + lane * 16;
  char* wp0 = &lds[kvh][0][qt * 4096 + lane * 16];
  char* wp1 = &lds[kvh][1][qt * 4096 + lane * 16];
  const char* KB0 = &lds[kvh][0][0];
  const char* KB1 = &lds[kvh][1][0];

  f32x16 O0 = {}, O1 = {}, psum = {};

  bf16x8 st0, st1, st2, st3;
#define SLOAD()                                                           \
  {                                                                       \
    st0 = *(const bf16x8*)(sp);                                           \
    st1 = *(const bf16x8*)(sp + 1024);                                    \
    st2 = *(const bf16x8*)(sp + 2048);                                    \
    st3 = *(const bf16x8*)(sp + 3072);                                    \
    sp += 16384;                                                          \
  }
#define SWRITE(WP)                                                       \
  {                                                                       \
    *(bf16x8*)(WP) = st0;                                                 \
    *(bf16x8*)((WP) + 1024) = st1;                                        \
    *(bf16x8*)((WP) + 2048) = st2;                                        \
    *(bf16x8*)((WP) + 3072) = st3;                                        \
  }

  auto compute = [&](const char* KB) {
    const char* VB = KB + 8192;
    // ---- S^T: mfma(A=K rows, B=Q); contiguous 1KB frag reads ----
    f32x16 s0 = {}, s1 = {};
    __builtin_amdgcn_s_setprio(1);
#pragma unroll
    for (int kc = 0; kc < 4; ++kc) {
      bf16x8 k0 = *(const bf16x8*)(KB + ((2 * kc + lhi1) << 9) + l31 * 16);
      bf16x8 k1 = *(const bf16x8*)(KB + 4096 + ((2 * kc + lhi1) << 9) + l31 * 16);
      s0 = __builtin_amdgcn_mfma_f32_32x32x16_bf16(k0, qf[kc], s0, 0, 0, 0);
      s1 = __builtin_amdgcn_mfma_f32_32x32x16_bf16(k1, qf[kc], s1, 0, 0, 0);
    }
    __builtin_amdgcn_s_setprio(0);

    // ---- P = exp2(S) (fixed max, raw v_exp_f32), deferred l-sum ----
#pragma unroll
    for (int r = 0; r < 16; ++r) {
      s0[r] = EXP2(s0[r]);
      s1[r] = EXP2(s1[r]);
    }
    psum += s0 + s1;

    // ---- pack P to bf16 words: w(s,rr) = P[kv=8s+4lhi1+2rr+{0,1}][q] ----
    u32 w0[8], w1[8];
#pragma unroll
    for (int s = 0; s < 4; ++s)
#pragma unroll
      for (int rr = 0; rr < 2; ++rr) {
        w0[s * 2 + rr] = pkbf(s0[4 * s + 2 * rr], s0[4 * s + 2 * rr + 1]);
        w1[s * 2 + rr] = pkbf(s1[4 * s + 2 * rr], s1[4 * s + 2 * rr + 1]);
      }

    // ---- PV via native 32x32x16; exchange via v_permlane32_swap_b32 ----
    __builtin_amdgcn_s_setprio(1);
#pragma unroll
    for (int t2 = 0; t2 < 2; ++t2) {
#pragma unroll
      for (int c2 = 0; c2 < 2; ++c2) {
        u32 aw0 = t2 ? w1[4 * c2 + 0] : w0[4 * c2 + 0];
        u32 aw1 = t2 ? w1[4 * c2 + 1] : w0[4 * c2 + 1];
        u32 bw0 = t2 ? w1[4 * c2 + 2] : w0[4 * c2 + 2];
        u32 bw1 = t2 ? w1[4 * c2 + 3] : w0[4 * c2 + 3];
        // swap(vdst=aw, vsrc=bw): aw'={aw.lo,bw.lo}=pb.u[0]; bw'={aw.hi,bw.hi}=pb.u[2]
        asm("v_permlane32_swap_b32 %0, %1" : "+v"(aw0), "+v"(bw0));
        asm("v_permlane32_swap_b32 %0, %1" : "+v"(aw1), "+v"(bw1));
        union { u32 u[4]; bf16x8 v; } pb;
        pb.u[0] = aw0;
        pb.u[1] = aw1;
        pb.u[2] = bw0;
        pb.u[3] = bw1;
        const int kb = t2 * 2 + c2;
        int base = ((2 * kb + lhi1) << 9) + l31 * 16;
        bf16x8 va = *(const bf16x8*)(VB + base);
        bf16x8 vb = *(const bf16x8*)(VB + 4096 + base);
        O0 = __builtin_amdgcn_mfma_f32_32x32x16_bf16(va, pb.v, O0, 0, 0, 0);
        O1 = __builtin_amdgcn_mfma_f32_32x32x16_bf16(vb, pb.v, O1, 0, 0, 0);
      }
    }
    __builtin_amdgcn_s_setprio(0);
  };

  // ---- prologue: tile0 -> buf0 ----
  SLOAD(); SWRITE(wp0);
  __syncthreads();

  // ---- main loop, unrolled x2: static buffer pointers ----
  for (int kt = 0; kt < 32; kt += 2) {
    SLOAD();                         // tile kt+1
    compute(KB0);                    // tile kt
    SWRITE(wp1);
    __syncthreads();
    if (kt + 2 < 32) SLOAD();        // tile kt+2
    compute(KB1);                    // tile kt+1
    if (kt + 2 < 32) SWRITE(wp0);
    __syncthreads();
  }

  // ---- l = horizontal sum of psum (once) ----
  f32x8 v8 = __builtin_shufflevector(psum, psum, 0, 1, 2, 3, 4, 5, 6, 7) +
             __builtin_shufflevector(psum, psum, 8, 9, 10, 11, 12, 13, 14, 15);
  f32x4 v4 = __builtin_shufflevector(v8, v8, 0, 1, 2, 3) +
             __builtin_shufflevector(v8, v8, 4, 5, 6, 7);
  float ss = (v4[0] + v4[1]) + (v4[2] + v4[3]);
  float l = ss + __shfl_xor(ss, 32);

  // ---- merge the two kv-halves of each q-tile via LDS (pure add) ----
  float* Olf = (float*)&lds[0][0][0];          // [8][64][32] f32 = 64KB
#pragma unroll
  for (int t2 = 0; t2 < 2; ++t2)
#pragma unroll
    for (int r = 0; r < 16; ++r) {
      int d = t2 * 32 + (r & 3) + 8 * (r >> 2) + 4 * lhi1;
      Olf[wid * 2048 + d * 32 + l31] = t2 ? O1[r] : O0[r];
    }
  if (lane < 32) Ll[wid][l31] = l;
  __syncthreads();

  const int pw = wid ^ 1;
  float inv = 1.f / (l + Ll[pw][l31]);
  const int dth = kvh;
  f32x16 Os = dth ? O1 : O0;
  bf16* op = ao + ((size_t)bh * NN + q0 + qt * 32 + l31) * 64 + dth * 32 + 4 * lhi1;
#pragma unroll
  for (int rg = 0; rg < 4; ++rg) {
    bf16x4 ov;
#pragma unroll
    for (int e = 0; e < 4; ++e) {
      int r = rg * 4 + e;
      int d = dth * 32 + e + 8 * rg + 4 * lhi1;
      float comb = Os[r] + Olf[pw * 2048 + d * 32 + l31];
      ov[e] = (bf16)(comb * inv);
    }
    *(bf16x4*)(op + 8 * rg) = ov;
  }
#undef SLOAD
#undef SWRITE
}

// ---------------------------------------------------------------------------
extern "C" void kernel_launch(void* const* d_in, const int* in_sizes, int n_in,
                              void* d_out, int out_size, void* d_ws, size_t ws_size,
                              hipStream_t stream) {
  const float* nuc = (const float*)d_in[0];
  const float* ele = (const float*)d_in[1];
  const float* Wq  = (const float*)d_in[2];
  const float* bq  = (const float*)d_in[3];
  const float* Wk  = (const float*)d_in[4];
  const float* bk  = (const float*)d_in[5];
  const float* Wv  = (const float*)d_in[6];
  const float* bv  = (const float*)d_in[7];
  const float* Wo  = (const float*)d_in[8];
  const float* bo  = (const float*)d_in[9];
  float* out = (float*)d_out;
  char* ws = (char*)d_ws;

  bf16* wtq  = (bf16*)(ws + 0);
  bf16* wtkv = (bf16*)(ws + 131072);     // wtk / wtv adjacent
  bf16* wtk  = (bf16*)(ws + 131072);
  bf16* wtv  = (bf16*)(ws + 262144);
  bf16* wto  = (bf16*)(ws + 393216);
  bf16* qhs  = (bf16*)(ws + 524288);     // [32][2048][64] bf16, 8MB
  char* kvt  = (char*)(ws + 8912896);    // [32][64][16KB] K/V images, 32MB
  bf16* aoh  = (bf16*)(ws + 42467328);   // [32][2048][64] bf16, 8MB

  prep_wt<<<dim3(256, 4), 256, 0, stream>>>(Wq, Wk, Wv, Wo, wtq, wtk, wtv, wto);

  // fused Q + K/V projections (Q scaled by 1/sqrt(64)*log2(e) for exp2 domain)
  gemm_qkv<<<dim3(1280), 256, 0, stream>>>(nuc, ele, wtq, wtkv, bq, bk, bv,
                                           qhs, kvt, 0.18033688011112042f);

  attn_kernel<<<dim3(512), 512, 0, stream>>>(qhs, kvt, aoh);

  gemm_out<<<dim3(256), 256, 0, stream>>>(aoh, wto, bo, out);
}